// Round 6
// baseline (2081.754 us; speedup 1.0000x reference)
//
#include <hip/hip_runtime.h>
#include <stdint.h>

// BasicNCA2D: 10 steps of depthwise7x7(reflect) -> concat -> fc0 -> BN(batch) -> relu -> fc1 -> masked update.
// B=8,H=256,W=256,C=16,HID=128. steps hardcoded to 10.
// RNG: JAX threefry, jax_threefry_partitionable=True: bits[i] = xor(threefry2x32(key,(0,i))).
//
// R5: nca_stats gram phase rewritten on MFMA. y staged bf16 channel-major in LDS
// (XOR-swizzled); per wave the 32x32 gram over its 64 cells = 6x mfma_16x16x32_bf16
// (upper-tri tiles; A-frag == B-frag by symmetry) + 4 MFMAs with B=ones for the first
// moments. Replaces ~1126 ds_read_b32 + 560 serial-chain FMAs per thread. LDS 37->20KB.
// partials/reduceA/reduceB/update unchanged from R4.

constexpr int Bn = 8;
constexpr int Hn = 256;
constexpr int Wn = 256;
constexpr int Cn = 16;
constexpr int HIDn = 128;
constexpr int NROW = Bn * Hn;              // 2048 (b,h) rows
constexpr int NCELLS = Bn * Hn * Wn;       // 524288
constexpr int NPAIR = 528;                 // 32*33/2 unique second moments of y
constexpr int NSTAT = 560;                 // pairs + 32 first moments
constexpr int STEPS = 10;

typedef __attribute__((ext_vector_type(8))) short bf16x8;
typedef __attribute__((ext_vector_type(4))) float f32x4;

__host__ __device__ inline uint32_t rotl32(uint32_t v, int r) {
  return (v << r) | (v >> (32 - r));
}

// Threefry-2x32, 20 rounds, exactly as jax/_src/prng.py
__host__ __device__ inline void tf2x32(uint32_t k0, uint32_t k1,
                                       uint32_t& x0, uint32_t& x1) {
  uint32_t k2 = k0 ^ k1 ^ 0x1BD11BDAu;
  x0 += k0; x1 += k1;
  x0 += x1; x1 = rotl32(x1, 13); x1 ^= x0;
  x0 += x1; x1 = rotl32(x1, 15); x1 ^= x0;
  x0 += x1; x1 = rotl32(x1, 26); x1 ^= x0;
  x0 += x1; x1 = rotl32(x1,  6); x1 ^= x0;
  x0 += k1; x1 += k2 + 1u;
  x0 += x1; x1 = rotl32(x1, 17); x1 ^= x0;
  x0 += x1; x1 = rotl32(x1, 29); x1 ^= x0;
  x0 += x1; x1 = rotl32(x1, 16); x1 ^= x0;
  x0 += x1; x1 = rotl32(x1, 24); x1 ^= x0;
  x0 += k2; x1 += k0 + 2u;
  x0 += x1; x1 = rotl32(x1, 13); x1 ^= x0;
  x0 += x1; x1 = rotl32(x1, 15); x1 ^= x0;
  x0 += x1; x1 = rotl32(x1, 26); x1 ^= x0;
  x0 += x1; x1 = rotl32(x1,  6); x1 ^= x0;
  x0 += k0; x1 += k1 + 3u;
  x0 += x1; x1 = rotl32(x1, 17); x1 ^= x0;
  x0 += x1; x1 = rotl32(x1, 29); x1 ^= x0;
  x0 += x1; x1 = rotl32(x1, 16); x1 ^= x0;
  x0 += x1; x1 = rotl32(x1, 24); x1 ^= x0;
  x0 += k1; x1 += k2 + 4u;
  x0 += x1; x1 = rotl32(x1, 13); x1 ^= x0;
  x0 += x1; x1 = rotl32(x1, 15); x1 ^= x0;
  x0 += x1; x1 = rotl32(x1, 26); x1 ^= x0;
  x0 += x1; x1 = rotl32(x1,  6); x1 ^= x0;
  x0 += k2; x1 += k0 + 5u;
}

__device__ inline float cell_mask(uint32_t fk0, uint32_t fk1, uint32_t ci) {
  uint32_t a = 0u, b2 = ci;
  tf2x32(fk0, fk1, a, b2);
  uint32_t bits = a ^ b2;
  float u = __uint_as_float((bits >> 9) | 0x3f800000u) - 1.0f;
  return (u > 0.5f) ? 1.0f : 0.0f;
}

// fp32 -> bf16 bits, round-to-nearest-even
__device__ inline uint32_t f2bf(float f) {
  uint32_t u = __float_as_uint(f);
  return (u + 0x7fffu + ((u >> 16) & 1u)) >> 16;
}

// depthwise 7x7 reflect conv for one cell; weights from LDS (broadcast reads).
__device__ inline void conv_cell(const float* __restrict__ xb, int hr, int w,
                                 const float* __restrict__ sW,
                                 float conv[16], float xc[16]) {
#pragma unroll
  for (int c = 0; c < 16; c++) conv[c] = 0.0f;
  for (int dy = 0; dy < 7; dy++) {
    int hh = hr + dy - 3;
    hh = (hh < 0) ? -hh : ((hh >= Hn) ? (2 * Hn - 2 - hh) : hh);
    const float* xr = xb + (size_t)hh * (Wn * Cn);
#pragma unroll
    for (int dx = 0; dx < 7; dx++) {
      int ww = w + dx - 3;
      ww = (ww < 0) ? -ww : ((ww >= Wn) ? (2 * Wn - 2 - ww) : ww);
      const float4* p = reinterpret_cast<const float4*>(xr + (size_t)ww * Cn);
      float4 v0 = p[0], v1 = p[1], v2 = p[2], v3 = p[3];
      const float* wt = sW + (dy * 7 + dx) * 16;
      conv[0]  += wt[0]  * v0.x; conv[1]  += wt[1]  * v0.y;
      conv[2]  += wt[2]  * v0.z; conv[3]  += wt[3]  * v0.w;
      conv[4]  += wt[4]  * v1.x; conv[5]  += wt[5]  * v1.y;
      conv[6]  += wt[6]  * v1.z; conv[7]  += wt[7]  * v1.w;
      conv[8]  += wt[8]  * v2.x; conv[9]  += wt[9]  * v2.y;
      conv[10] += wt[10] * v2.z; conv[11] += wt[11] * v2.w;
      conv[12] += wt[12] * v3.x; conv[13] += wt[13] * v3.y;
      conv[14] += wt[14] * v3.z; conv[15] += wt[15] * v3.w;
      if (dy == 3 && dx == 3) {
        xc[0] = v0.x;  xc[1] = v0.y;  xc[2] = v0.z;  xc[3] = v0.w;
        xc[4] = v1.x;  xc[5] = v1.y;  xc[6] = v1.z;  xc[7] = v1.w;
        xc[8] = v2.x;  xc[9] = v2.y;  xc[10] = v2.z; xc[11] = v2.w;
        xc[12] = v3.x; xc[13] = v3.y; xc[14] = v3.z; xc[15] = v3.w;
      }
    }
  }
}

// XCD-contiguous row mapping for the conv pass (halo-row L2 reuse).
__device__ inline int swz_row(int bid) { return ((bid & 7) << 8) | (bid >> 3); }

// one-time prep:
//  w0bf [n=128][k=32] bf16 : w0bf[n*32+k] = bf16(fc0w[k*128+n])
//  w1p  [c=16][kl=128] bf16: n = (kl&7)*16 + (kl>>3); w1p[c*128+kl] = bf16(fc1w[n*16+c])
__global__ __launch_bounds__(256) void nca_prep(const float* __restrict__ fc0w,
                                                const float* __restrict__ fc1w,
                                                uint16_t* __restrict__ w0bf,
                                                uint16_t* __restrict__ w1p) {
  int i = blockIdx.x * 256 + threadIdx.x;  // 0..6143
  if (i < 4096) {
    int n = i >> 5, k = i & 31;
    w0bf[i] = (uint16_t)f2bf(fc0w[k * HIDn + n]);
  } else {
    int j = i - 4096;
    int c = j >> 7, kl = j & 127;
    int n = (kl & 7) * 16 + (kl >> 3);
    w1p[j] = (uint16_t)f2bf(fc1w[n * 16 + c]);
  }
}

// Stats pass: conv per cell -> y; ybf to global; y bf16 channel-major to LDS
// (swizzled); per-wave 32x32 gram of its 64 cells via MFMA (+ moments via B=ones);
// block-reduce 4 wave partials; emit upper-tri 528 + 32 moments.
__global__ __launch_bounds__(256) void nca_stats(
    const float* __restrict__ x, const float* __restrict__ p0w,
    const float* __restrict__ p0b, float* __restrict__ partials,
    uint16_t* __restrict__ ybf) {
  __shared__ float sW[784];
  __shared__ float sB[16];
  __shared__ __align__(16) short sYT[32 * 256];  // bf16 ch-major, elem (c,k) at c*256+(k^((c&7)<<3)); reused as f32 gram[4][1024]
  __shared__ float sMom[4 * 32];
  int t = threadIdx.x;
  int lane = t & 63, wid = t >> 6;
  int row = swz_row(blockIdx.x);
  int b = row >> 8, hr = row & 255;
  for (int i = t; i < 784; i += 256) sW[i] = p0w[i];
  if (t < 16) sB[t] = p0b[t];
  __syncthreads();

  const float* xb = x + (size_t)b * (Hn * Wn * Cn);
  float conv[16], xc[16];
  conv_cell(xb, hr, t, sW, conv, xc);
  float yv[32];
#pragma unroll
  for (int c = 0; c < 16; c++) {
    yv[c] = xc[c];
    yv[16 + c] = conv[c] + sB[c];
  }
  // bf16 pack; write global ybf (update pass input)
  size_t ci = (size_t)row * 256 + t;
  uint32_t pk[16];
#pragma unroll
  for (int q = 0; q < 16; q++)
    pk[q] = f2bf(yv[2 * q]) | (f2bf(yv[2 * q + 1]) << 16);
  uint4* yp = reinterpret_cast<uint4*>(ybf + ci * 32);
  yp[0] = make_uint4(pk[0], pk[1], pk[2], pk[3]);
  yp[1] = make_uint4(pk[4], pk[5], pk[6], pk[7]);
  yp[2] = make_uint4(pk[8], pk[9], pk[10], pk[11]);
  yp[3] = make_uint4(pk[12], pk[13], pk[14], pk[15]);
  // bf16 channel-major to LDS (same bf16 values), swizzled
#pragma unroll
  for (int c = 0; c < 32; c++) {
    uint16_t hv = (c & 1) ? (uint16_t)(pk[c >> 1] >> 16) : (uint16_t)(pk[c >> 1] & 0xffffu);
    sYT[c * 256 + (t ^ ((c & 7) << 3))] = (short)hv;
  }
  __syncthreads();

  // per-wave gram over cells [wid*64, wid*64+64)
  int colc = lane & 15, kg = lane >> 4;
  f32x4 g00 = {0.f, 0.f, 0.f, 0.f}, g01 = g00, g11 = g00, m0 = g00, m1 = g00;
  bf16x8 ones;
#pragma unroll
  for (int e = 0; e < 8; e++) ones[e] = (short)0x3F80;  // bf16 1.0
#pragma unroll
  for (int s2 = 0; s2 < 2; s2++) {
    int kbase = wid * 64 + s2 * 32 + kg * 8;
    int ch0 = colc, ch1 = 16 + colc;
    bf16x8 f0 = *reinterpret_cast<const bf16x8*>(sYT + ch0 * 256 + (kbase ^ ((ch0 & 7) << 3)));
    bf16x8 f1 = *reinterpret_cast<const bf16x8*>(sYT + ch1 * 256 + (kbase ^ ((ch1 & 7) << 3)));
    g00 = __builtin_amdgcn_mfma_f32_16x16x32_bf16(f0, f0, g00, 0, 0, 0);
    g01 = __builtin_amdgcn_mfma_f32_16x16x32_bf16(f0, f1, g01, 0, 0, 0);
    g11 = __builtin_amdgcn_mfma_f32_16x16x32_bf16(f1, f1, g11, 0, 0, 0);
    m0  = __builtin_amdgcn_mfma_f32_16x16x32_bf16(f0, ones, m0, 0, 0, 0);
    m1  = __builtin_amdgcn_mfma_f32_16x16x32_bf16(f1, ones, m1, 0, 0, 0);
  }
  // moments (all cols of m0/m1 identical; take col 0 lanes)
  if (colc == 0) {
#pragma unroll
    for (int r = 0; r < 4; r++) {
      sMom[wid * 32 + kg * 4 + r] = m0[r];
      sMom[wid * 32 + 16 + kg * 4 + r] = m1[r];
    }
  }
  __syncthreads();  // all waves done reading sYT -> safe to alias as gram
  float* sG = reinterpret_cast<float*>(sYT);  // [4][32][32]
  {
    float* sGw = sG + wid * 1024;
#pragma unroll
    for (int r = 0; r < 4; r++) {
      int rr = kg * 4 + r;
      sGw[rr * 32 + colc] = g00[r];              // rows 0-15, cols 0-15
      sGw[rr * 32 + 16 + colc] = g01[r];         // rows 0-15, cols 16-31
      sGw[(16 + rr) * 32 + 16 + colc] = g11[r];  // rows 16-31, cols 16-31
    }
  }
  __syncthreads();

  float* outp = partials + (size_t)row * NSTAT;
  for (int e = t; e < NSTAT; e += 256) {
    float acc;
    if (e < NPAIR) {
      int ee = e, i = 0;
      while (ee >= (32 - i)) { ee -= (32 - i); i++; }
      int j = i + ee;
      int gi = i * 32 + j;
      acc = sG[gi] + sG[1024 + gi] + sG[2048 + gi] + sG[3072 + gi];
    } else {
      int i = e - NPAIR;
      acc = sMom[i] + sMom[32 + i] + sMom[64 + i] + sMom[96 + i];
    }
    outp[e] = acc;
  }
}

// Reduce partials across the 2048 rows (fp64) -> sred[560]
__global__ __launch_bounds__(256) void nca_reduceA(
    const float* __restrict__ partials, double* __restrict__ sred) {
  __shared__ double red[256];
  int e = blockIdx.x;
  int t = threadIdx.x;
  double acc = 0.0;
  for (int row = t; row < NROW; row += 256)
    acc += (double)partials[(size_t)row * NSTAT + e];
  red[t] = acc;
  __syncthreads();
  for (int s2 = 128; s2 > 0; s2 >>= 1) {
    if (t < s2) red[t] += red[t + s2];
    __syncthreads();
  }
  if (t == 0) sred[e] = red[0];
}

// Per-hid BN constants from moments. fc0_b cancels exactly.
__global__ __launch_bounds__(128) void nca_reduceB(
    const double* __restrict__ sred, const float* __restrict__ fc0w,
    const float* __restrict__ gamma, const float* __restrict__ beta,
    float* __restrict__ ss) {
  __shared__ double S[NSTAT];
  int t = threadIdx.x;
  for (int i = t; i < NSTAT; i += 128) S[i] = sred[i];
  __syncthreads();
  double wv[32];
#pragma unroll
  for (int k = 0; k < 32; k++) wv[k] = (double)fc0w[k * HIDn + t];
  double mean_g = 0.0, q = 0.0;
  int e = 0;
  for (int i = 0; i < 32; i++) {
    mean_g += wv[i] * S[NPAIR + i];
    q += wv[i] * wv[i] * S[e]; e++;
    for (int j = i + 1; j < 32; j++) { q += 2.0 * wv[i] * wv[j] * S[e]; e++; }
  }
  const double invN = 1.0 / (double)NCELLS;
  mean_g *= invN; q *= invN;
  double var = q - mean_g * mean_g;
  double scale = (double)gamma[t] / sqrt(var + 1e-5);
  ss[2 * t]     = (float)scale;
  ss[2 * t + 1] = (float)((double)beta[t] - mean_g * scale);
}

// MFMA update: per wave, 16-cell M-tiles. fc0: 8x mfma_16x16x32_bf16 (K=32);
// BN+relu on f32 accs; repack bf16 via per-wave LDS (XOR swizzle, k-permuted);
// fc1: 4x mfma_16x16x32_bf16 (K=128); residual+mask epilogue.
__global__ __launch_bounds__(256) void nca_update_mfma(
    const float* __restrict__ x, const uint16_t* __restrict__ ybf,
    const uint16_t* __restrict__ w0bf, const uint16_t* __restrict__ w1p,
    const float* __restrict__ ssg, float* __restrict__ xout,
    uint32_t fk0, uint32_t fk1) {
  __shared__ short hbuf[4][16 * 128];  // 4KB per wave
  int t = threadIdx.x;
  int lane = t & 63, wid = t >> 6;
  int col = lane & 15, g = lane >> 4;
  short* hb = hbuf[wid];

  // hoisted operand fragments (tile-invariant)
  bf16x8 b0[8];
#pragma unroll
  for (int nt = 0; nt < 8; nt++) {
    int n = nt * 16 + col;
    b0[nt] = *reinterpret_cast<const bf16x8*>(w0bf + n * 32 + g * 8);
  }
  bf16x8 b2[4];
#pragma unroll
  for (int kk = 0; kk < 4; kk++)
    b2[kk] = *reinterpret_cast<const bf16x8*>(w1p + col * 128 + kk * 32 + g * 8);
  float sc[8], sh[8];
#pragma unroll
  for (int nt = 0; nt < 8; nt++) {
    float2 v = reinterpret_cast<const float2*>(ssg)[nt * 16 + col];
    sc[nt] = v.x; sh[nt] = v.y;
  }

  uint32_t waveBase = (uint32_t)blockIdx.x * 1024u + (uint32_t)wid * 256u;
  for (int grp = 0; grp < 4; grp++) {
    uint32_t grpBase = waveBase + (uint32_t)grp * 64u;
    float mval = cell_mask(fk0, fk1, grpBase + (uint32_t)lane);
#pragma unroll 1
    for (int tt = 0; tt < 4; tt++) {
      uint32_t tb = grpBase + (uint32_t)tt * 16u;
      // A0 frag: wave reads contiguous 1KB from ybf
      bf16x8 a0 = *reinterpret_cast<const bf16x8*>(
          ybf + (size_t)(tb + col) * 32 + g * 8);
      // residual x prefetch
      float xv[4];
#pragma unroll
      for (int r = 0; r < 4; r++)
        xv[r] = x[(size_t)(tb + g * 4 + r) * Cn + col];
      // fc0
      f32x4 h[8];
#pragma unroll
      for (int nt = 0; nt < 8; nt++) {
        f32x4 z = {0.f, 0.f, 0.f, 0.f};
        h[nt] = __builtin_amdgcn_mfma_f32_16x16x32_bf16(a0, b0[nt], z, 0, 0, 0);
      }
      // BN + relu + bf16 pack -> LDS [m][k_lds], k_lds = col16*8 + nt, XOR swizzle
#pragma unroll
      for (int r = 0; r < 4; r++) {
        int m = g * 4 + r;
        uint32_t u[4];
#pragma unroll
        for (int q = 0; q < 4; q++) {
          float v0 = fmaxf(h[2 * q][r] * sc[2 * q] + sh[2 * q], 0.0f);
          float v1 = fmaxf(h[2 * q + 1][r] * sc[2 * q + 1] + sh[2 * q + 1], 0.0f);
          u[q] = f2bf(v0) | (f2bf(v1) << 16);
        }
        int idx = m * 128 + ((col * 8) ^ ((m & 7) << 3));
        *reinterpret_cast<uint4*>(hb + idx) = make_uint4(u[0], u[1], u[2], u[3]);
      }
      // fc1 over k_lds (w1p permuted identically -> permutation cancels)
      f32x4 dx = {0.f, 0.f, 0.f, 0.f};
#pragma unroll
      for (int kk = 0; kk < 4; kk++) {
        int idx = col * 128 + (((kk * 32) + g * 8) ^ ((col & 7) << 3));
        bf16x8 a2 = *reinterpret_cast<const bf16x8*>(hb + idx);
        dx = __builtin_amdgcn_mfma_f32_16x16x32_bf16(a2, b2[kk], dx, 0, 0, 0);
      }
      // epilogue: o = x + mask*dx (channel 0 preserved)
#pragma unroll
      for (int r = 0; r < 4; r++) {
        int m = g * 4 + r;
        float mk = __shfl(mval, tt * 16 + m);
        float o = xv[r] + dx[r] * mk;
        if (col == 0) o = xv[r];
        xout[(size_t)(tb + m) * Cn + col] = o;
      }
    }
  }
}

extern "C" void kernel_launch(void* const* d_in, const int* in_sizes, int n_in,
                              void* d_out, int out_size, void* d_ws, size_t ws_size,
                              hipStream_t stream) {
  (void)in_sizes; (void)n_in; (void)out_size; (void)ws_size;
  const float* x0    = (const float*)d_in[0];
  const float* p0w   = (const float*)d_in[1];
  const float* p0b   = (const float*)d_in[2];
  const float* fc0w  = (const float*)d_in[3];
  // d_in[4] = fc0_b: cancels exactly in BatchNorm -> unused
  const float* gamma = (const float*)d_in[5];
  const float* beta  = (const float*)d_in[6];
  const float* fc1w  = (const float*)d_in[7];
  // d_in[8] = steps (=10, hardcoded)

  // workspace layout (~72 MB)
  size_t off = 0;
  float* ws_x = (float*)((char*)d_ws + off); off += (size_t)NCELLS * Cn * 4;        // 33.5 MiB
  uint16_t* ws_ybf = (uint16_t*)((char*)d_ws + off); off += (size_t)NCELLS * 32 * 2; // 33.5 MiB
  float* ws_part = (float*)((char*)d_ws + off); off += (size_t)NROW * NSTAT * 4;    // 4.6 MiB
  double* ws_sred = (double*)((char*)d_ws + off); off += (size_t)NSTAT * 8;
  float* ws_ss = (float*)((char*)d_ws + off); off += (size_t)HIDn * 2 * 4;
  uint16_t* ws_w0bf = (uint16_t*)((char*)d_ws + off); off += 4096 * 2;
  uint16_t* ws_w1p = (uint16_t*)((char*)d_ws + off); off += 2048 * 2;
  float* out = (float*)d_out;

  nca_prep<<<24, 256, 0, stream>>>(fc0w, fc1w, ws_w0bf, ws_w1p);

  const float* xin = x0;
  for (int s = 0; s < STEPS; s++) {
    uint32_t fk0 = 0u, fk1 = (uint32_t)s;
    tf2x32(0u, 42u, fk0, fk1);
    float* xo = (((STEPS - 1 - s) & 1) != 0) ? ws_x : out;

    nca_stats<<<NROW, 256, 0, stream>>>(xin, p0w, p0b, ws_part, ws_ybf);
    nca_reduceA<<<NSTAT, 256, 0, stream>>>(ws_part, ws_sred);
    nca_reduceB<<<1, 128, 0, stream>>>(ws_sred, fc0w, gamma, beta, ws_ss);
    nca_update_mfma<<<NCELLS / 1024, 256, 0, stream>>>(xin, ws_ybf, ws_w0bf,
                                                       ws_w1p, ws_ss, xo, fk0, fk1);
    xin = xo;
  }
}